// Round 1
// baseline (1834.802 us; speedup 1.0000x reference)
//
#include <hip/hip_runtime.h>
#include <hip/hip_bf16.h>

// scatter_mean over a SORTED residue index.
//   atom_features: [N=2,000,000, D=128] fp32
//   residue_index: [N] int32 (sorted ascending, values in [0, R))
//   out:           [R=250,000, D=128] fp32  = segment_sum / max(count,1)
//
// One wave (64 lanes) per residue. Segment bounds found via wave-uniform
// binary search (index array is 8 MB -> L2/L3 resident; upper tree levels
// stay hot). Each lane owns 2 columns (float2): a full 128-float row is one
// coalesced 512 B wave access. Rows of one residue are contiguous (sorted),
// so feature reads stream linearly through HBM.

__device__ __forceinline__ int lower_bound(const int* __restrict__ idx,
                                           int n, int val) {
    int lo = 0, hi = n;
    while (lo < hi) {
        int mid = (lo + hi) >> 1;
        if (idx[mid] < val) lo = mid + 1;
        else hi = mid;
    }
    return lo;
}

__global__ __launch_bounds__(256) void residue_pool_kernel(
        const float* __restrict__ feat,   // [N,128]
        const int* __restrict__ ridx,     // [N]
        float* __restrict__ out,          // [R,128]
        int n_atoms, int n_res) {
    const int gtid = blockIdx.x * blockDim.x + threadIdx.x;
    const int wave = gtid >> 6;          // one wave per residue
    const int lane = threadIdx.x & 63;
    if (wave >= n_res) return;

    const int r = wave;
    // wave-uniform binary searches (same addresses across lanes -> broadcast)
    const int start = lower_bound(ridx, n_atoms, r);
    const int end   = lower_bound(ridx, n_atoms, r + 1);

    const float2* __restrict__ f2 = (const float2*)feat;  // row stride 64
    float2 acc = make_float2(0.f, 0.f);
    for (int i = start; i < end; ++i) {
        float2 v = f2[(size_t)i * 64 + lane];
        acc.x += v.x;
        acc.y += v.y;
    }

    const int cnt = end - start;
    const float scale = 1.0f / (float)(cnt > 0 ? cnt : 1);
    float2* o2 = (float2*)out;
    o2[(size_t)r * 64 + lane] = make_float2(acc.x * scale, acc.y * scale);
}

extern "C" void kernel_launch(void* const* d_in, const int* in_sizes, int n_in,
                              void* d_out, int out_size, void* d_ws, size_t ws_size,
                              hipStream_t stream) {
    const float* feat = (const float*)d_in[0];
    const int*   ridx = (const int*)d_in[1];
    float* out = (float*)d_out;

    const int n_atoms = in_sizes[1];          // 2,000,000
    const int n_res   = out_size / 128;       // 250,000

    const int threads = 256;                  // 4 waves/block -> 4 residues/block
    const long long total_threads = (long long)n_res * 64;
    const int blocks = (int)((total_threads + threads - 1) / threads);

    residue_pool_kernel<<<blocks, threads, 0, stream>>>(feat, ridx, out,
                                                        n_atoms, n_res);
}